// Round 5
// baseline (946437.305 us; speedup 1.0000x reference)
//
#include <hip/hip_runtime.h>
#include <hip/hip_bf16.h>
#include <stdint.h>

// Problem: S=512, N=64, E=256, NH=8, HD=32, LH=512.
// Pipeline: convert -> qkv -> attn -> outproj -> gates GEMM -> persistent LSTM -> final proj.
// R5 = R4 (XCD-local LSTM) + robust slot claim:
//   - overlaunch 512 WGs; slot = atomicAdd(cnt[XCC_ID]); slot>=32 -> exit immediately.
//     86KB LDS caps residency at 32 WG/XCD, CP refills freed CUs until every XCD has 32
//     stayers -> complete groups guaranteed, no aliasing (R4 hung on claim imbalance).
//   - bounded flag poll (20k tries) -> sync bugs fail fast instead of hanging the GPU.
// All step-loop traffic (h ring, flags) stays inside one XCD's coherent L2.

typedef __attribute__((ext_vector_type(8))) short bf16x8;
typedef __attribute__((ext_vector_type(4))) float f32x4;

__device__ __forceinline__ unsigned short f2bf(float f){
  unsigned u = __float_as_uint(f);
  u += 0x7FFFu + ((u >> 16) & 1u);          // RNE
  return (unsigned short)(u >> 16);
}
__device__ __forceinline__ float b2f(unsigned short h){
  return __uint_as_float(((unsigned)h) << 16);
}
__device__ __forceinline__ ushort4 f4tobf(float4 f){
  ushort4 o; o.x=f2bf(f.x); o.y=f2bf(f.y); o.z=f2bf(f.z); o.w=f2bf(f.w); return o;
}

// ---------------- workspace layout (bytes) ----------------
// flags:    [0x0,      0x4000)   8 groups x 32 slots, 64B stride
// cnt:      [0x4000,   0x4020)   8 ints, per-XCD slot claim
// pooled:   [0x30000,  0x50000)  64x512 f32
// w_ih bf16:[0x50000,  0x250000)
// combined: [0x800000, 0x2800000) 32768x512 bf16; REUSED by k_lstm as h-ring:
//           ring[st][g] = 8KB (8 batches x 512 units bf16), 64KB/step, 32MB total
// gates:    [0x3000000,0xB000000) layout [m][u][gate] = m*2048 + u*4 + gate (aliases q/k/v/ctx)
// q:0x3000000 k:0x4000000 v:0x5000000 ctx:0x6000000 (each 16MB bf16)
// total required ws: 0xB000000 = 184,549,376 B

// K0: w_ih fp32->bf16, and x fp32 -> combined[:, 0:256] bf16
__global__ __launch_bounds__(256) void k_convert(const float* __restrict__ wih,
                                                 const float* __restrict__ x,
                                                 unsigned short* __restrict__ wih_bf,
                                                 unsigned short* __restrict__ comb){
  size_t i = ((size_t)blockIdx.x * 256 + threadIdx.x) * 4;
  if (i < 1048576){
    float4 f = *(const float4*)(wih + i);
    *(ushort4*)(wih_bf + i) = f4tobf(f);
  } else {
    size_t j = i - 1048576;
    if (j < 8388608){
      float4 f = *(const float4*)(x + j);
      size_t m = j >> 8, c = j & 255;
      *(ushort4*)(comb + m*512 + c) = f4tobf(f);
    }
  }
}

// K1: qkv = x @ in_proj_w.T + b ; scale folded into q; writes q/k [n][h][s][d], v transposed [n][h][d][s]
__global__ __launch_bounds__(256) void k_qkv(const unsigned short* __restrict__ xb,
                                             const float* __restrict__ w,
                                             const float* __restrict__ bias,
                                             unsigned short* __restrict__ q,
                                             unsigned short* __restrict__ kk,
                                             unsigned short* __restrict__ v){
  const int nt = blockIdx.x;    // 0..11
  const int mt = blockIdx.y;    // 0..511  (= s, since M-row = s*64+n)
  __shared__ unsigned short Bs[64][264];
  const int t = threadIdx.x;
  { // stage+convert B tile (in_proj_w rows nt*64..+64, k 0..256)
    int row = t >> 2, c0 = (t & 3) * 64;
    const float* src = w + (size_t)(nt*64 + row)*256 + c0;
    #pragma unroll
    for (int i = 0; i < 64; i += 4){
      float4 f = *(const float4*)(src + i);
      *(ushort4*)&Bs[row][c0 + i] = f4tobf(f);
    }
  }
  __syncthreads();
  const int w4 = t >> 6, l = t & 63, lr = l & 15, lc = l >> 4;
  f32x4 acc[4];
  #pragma unroll
  for (int i = 0; i < 4; ++i) acc[i] = (f32x4){0.f,0.f,0.f,0.f};
  const size_t arow = (size_t)(mt*64 + w4*16 + lr) * 512;  // A from combined (bf16 x)
  #pragma unroll
  for (int kt = 0; kt < 8; ++kt){
    bf16x8 a = *(const bf16x8*)(xb + arow + kt*32 + lc*8);
    #pragma unroll
    for (int n4 = 0; n4 < 4; ++n4){
      bf16x8 b = *(const bf16x8*)&Bs[n4*16 + lr][kt*32 + lc*8];
      acc[n4] = __builtin_amdgcn_mfma_f32_16x16x32_bf16(a, b, acc[n4], 0, 0, 0);
    }
  }
  const int s = mt;
  #pragma unroll
  for (int n4 = 0; n4 < 4; ++n4){
    int ncol = nt*64 + n4*16 + lr;
    float bv = bias[ncol];
    int which = ncol >> 8, rem = ncol & 255, hh = rem >> 5, d = rem & 31;
    #pragma unroll
    for (int reg = 0; reg < 4; ++reg){
      int nb = w4*16 + lc*4 + reg;   // batch
      float val = acc[n4][reg] + bv;
      if (which == 0){
        val *= 0.17677669529663687f;  // 1/sqrt(32)
        q[((size_t)(nb*8 + hh)*512 + s)*32 + d] = f2bf(val);
      } else if (which == 1){
        kk[((size_t)(nb*8 + hh)*512 + s)*32 + d] = f2bf(val);
      } else {
        v[((size_t)(nb*8 + hh)*32 + d)*512 + s] = f2bf(val);
      }
    }
  }
}

// K2: attention for one (n,h); Q-tile=32, full-S bf16 score strip in LDS, exp recomputed into PV A-frags
__global__ __launch_bounds__(256) void k_attn(const unsigned short* __restrict__ q,
                                              const unsigned short* __restrict__ k,
                                              const unsigned short* __restrict__ v,
                                              unsigned short* __restrict__ ctx){
  const int nh = blockIdx.x;
  const int n = nh >> 3, h = nh & 7;
  __shared__ unsigned short sc[32][520];
  __shared__ float red[32][8];
  __shared__ float rowmax[32], rowinv[32];
  const unsigned short* qb = q + (size_t)nh * 512 * 32;
  const unsigned short* kb = k + (size_t)nh * 512 * 32;
  const unsigned short* vb = v + (size_t)nh * 32 * 512;
  const int t = threadIdx.x, w4 = t >> 6, l = t & 63, lr = l & 15, lc = l >> 4;
  const int r = t >> 3, cc = t & 7;
  for (int qt = 0; qt < 16; ++qt){
    const int s0 = qt * 32;
    bf16x8 aq0 = *(const bf16x8*)(qb + (size_t)(s0 + lr)*32 + lc*8);
    bf16x8 aq1 = *(const bf16x8*)(qb + (size_t)(s0 + 16 + lr)*32 + lc*8);
    #pragma unroll
    for (int j = 0; j < 8; ++j){
      int ntl = w4*8 + j;
      bf16x8 bk = *(const bf16x8*)(kb + (size_t)(ntl*16 + lr)*32 + lc*8);
      f32x4 d0 = (f32x4){0.f,0.f,0.f,0.f}, d1 = (f32x4){0.f,0.f,0.f,0.f};
      d0 = __builtin_amdgcn_mfma_f32_16x16x32_bf16(aq0, bk, d0, 0, 0, 0);
      d1 = __builtin_amdgcn_mfma_f32_16x16x32_bf16(aq1, bk, d1, 0, 0, 0);
      #pragma unroll
      for (int reg = 0; reg < 4; ++reg){
        sc[lc*4 + reg][ntl*16 + lr]      = f2bf(d0[reg]);
        sc[16 + lc*4 + reg][ntl*16 + lr] = f2bf(d1[reg]);
      }
    }
    __syncthreads();
    float pm = -1e30f;
    for (int i = 0; i < 64; ++i) pm = fmaxf(pm, b2f(sc[r][cc + 8*i]));
    red[r][cc] = pm;
    __syncthreads();
    float mfull = red[r][0];
    #pragma unroll
    for (int i = 1; i < 8; ++i) mfull = fmaxf(mfull, red[r][i]);
    rowmax[r] = mfull;   // benign same-value race across the 8 threads of a row
    __syncthreads();
    float sum = 0.f;
    for (int i = 0; i < 64; ++i) sum += __expf(b2f(sc[r][cc + 8*i]) - mfull);
    red[r][cc] = sum;
    __syncthreads();
    float ss = 0.f;
    #pragma unroll
    for (int i = 0; i < 8; ++i) ss += red[r][i];
    rowinv[r] = 1.f / ss;
    __syncthreads();
    // PV: each wave one 16x16 tile of the 32x32 O
    const int mt = w4 >> 1, ntd = w4 & 1;
    const int arow = mt*16 + lr;
    const float mrow = rowmax[arow];
    f32x4 o = (f32x4){0.f,0.f,0.f,0.f};
    for (int kt = 0; kt < 16; ++kt){
      bf16x8 sv = *(const bf16x8*)&sc[arow][kt*32 + lc*8];
      bf16x8 ap;
      #pragma unroll
      for (int e = 0; e < 8; ++e){
        float p = __expf(b2f((unsigned short)sv[e]) - mrow);
        ap[e] = (short)f2bf(p);
      }
      bf16x8 bv = *(const bf16x8*)(vb + (size_t)(ntd*16 + lr)*512 + kt*32 + lc*8);
      o = __builtin_amdgcn_mfma_f32_16x16x32_bf16(ap, bv, o, 0, 0, 0);
    }
    #pragma unroll
    for (int reg = 0; reg < 4; ++reg){
      int row = mt*16 + lc*4 + reg;
      int d = ntd*16 + lr;
      float val = o[reg] * rowinv[row];
      ctx[((size_t)(s0 + row)*64 + n)*256 + h*32 + d] = f2bf(val);
    }
    __syncthreads();
  }
}

// K3: attn_out = ctx @ mha_out_w.T + b -> combined[:, 256:512]
__global__ __launch_bounds__(256) void k_outproj(const unsigned short* __restrict__ ctx,
                                                 const float* __restrict__ w,
                                                 const float* __restrict__ bias,
                                                 unsigned short* __restrict__ comb){
  const int nt = blockIdx.x;   // 0..3
  const int mt = blockIdx.y;   // 0..511
  __shared__ unsigned short Bs[64][264];
  const int t = threadIdx.x;
  {
    int row = t >> 2, c0 = (t & 3) * 64;
    const float* src = w + (size_t)(nt*64 + row)*256 + c0;
    #pragma unroll
    for (int i = 0; i < 64; i += 4){
      float4 f = *(const float4*)(src + i);
      *(ushort4*)&Bs[row][c0 + i] = f4tobf(f);
    }
  }
  __syncthreads();
  const int w4 = t >> 6, l = t & 63, lr = l & 15, lc = l >> 4;
  f32x4 acc[4];
  #pragma unroll
  for (int i = 0; i < 4; ++i) acc[i] = (f32x4){0.f,0.f,0.f,0.f};
  const size_t arow = (size_t)(mt*64 + w4*16 + lr) * 256;
  #pragma unroll
  for (int kt = 0; kt < 8; ++kt){
    bf16x8 a = *(const bf16x8*)(ctx + arow + kt*32 + lc*8);
    #pragma unroll
    for (int n4 = 0; n4 < 4; ++n4){
      bf16x8 b = *(const bf16x8*)&Bs[n4*16 + lr][kt*32 + lc*8];
      acc[n4] = __builtin_amdgcn_mfma_f32_16x16x32_bf16(a, b, acc[n4], 0, 0, 0);
    }
  }
  #pragma unroll
  for (int n4 = 0; n4 < 4; ++n4){
    int ncol = nt*64 + n4*16 + lr;
    float bv = bias[ncol];
    #pragma unroll
    for (int reg = 0; reg < 4; ++reg){
      int m = mt*64 + w4*16 + lc*4 + reg;
      comb[(size_t)m*512 + 256 + ncol] = f2bf(acc[n4][reg] + bv);
    }
  }
}

// K4: gates_x = combined @ w_ih.T + (b_ih + b_hh), 128x128 tiles, BK=64.
// Output layout for k_lstm: gates[m][u][gate] = m*2048 + u*4 + gate  (m = st*64 + n).
__global__ __launch_bounds__(256) void k_gates(const unsigned short* __restrict__ A,
                                               const unsigned short* __restrict__ B,
                                               const float* __restrict__ bih,
                                               const float* __restrict__ bhh,
                                               unsigned short* __restrict__ gates){
  const int ntile = blockIdx.x;  // 0..15
  const int mtile = blockIdx.y;  // 0..255
  __shared__ unsigned short As[128][72], Bss[128][72];
  const int t = threadIdx.x, w4 = t >> 6, l = t & 63, lr = l & 15, lc = l >> 4;
  const int wm = w4 >> 1, wn = w4 & 1;
  f32x4 acc[4][4];
  #pragma unroll
  for (int i = 0; i < 4; ++i)
    #pragma unroll
    for (int j = 0; j < 4; ++j) acc[i][j] = (f32x4){0.f,0.f,0.f,0.f};
  const int srow = t >> 1, half = t & 1;
  const unsigned short* sa = A + (size_t)(mtile*128 + srow)*512 + half*32;
  const unsigned short* sb = B + (size_t)(ntile*128 + srow)*512 + half*32;
  for (int kkk = 0; kkk < 8; ++kkk){
    #pragma unroll
    for (int i = 0; i < 4; ++i){
      *(uint4*)&As [srow][half*32 + i*8] = *(const uint4*)(sa + kkk*64 + i*8);
      *(uint4*)&Bss[srow][half*32 + i*8] = *(const uint4*)(sb + kkk*64 + i*8);
    }
    __syncthreads();
    #pragma unroll
    for (int kt = 0; kt < 2; ++kt){
      bf16x8 af[4], bfr[4];
      #pragma unroll
      for (int i = 0; i < 4; ++i) af[i]  = *(const bf16x8*)&As [wm*64 + i*16 + lr][kt*32 + lc*8];
      #pragma unroll
      for (int i = 0; i < 4; ++i) bfr[i] = *(const bf16x8*)&Bss[wn*64 + i*16 + lr][kt*32 + lc*8];
      #pragma unroll
      for (int i = 0; i < 4; ++i)
        #pragma unroll
        for (int j = 0; j < 4; ++j)
          acc[i][j] = __builtin_amdgcn_mfma_f32_16x16x32_bf16(af[i], bfr[j], acc[i][j], 0, 0, 0);
    }
    __syncthreads();
  }
  #pragma unroll
  for (int i = 0; i < 4; ++i){
    #pragma unroll
    for (int j = 0; j < 4; ++j){
      int ncol = ntile*128 + wn*64 + j*16 + lr;
      int gate = ncol >> 9, u = ncol & 511;
      float bsum = bih[ncol] + bhh[ncol];
      #pragma unroll
      for (int reg = 0; reg < 4; ++reg){
        int m = mtile*128 + wm*64 + i*16 + lc*4 + reg;
        gates[(size_t)m*2048 + u*4 + gate] = f2bf(acc[i][j][reg] + bsum);
      }
    }
  }
}

// K5: persistent LSTM, XCD-local. Launch 512 WGs; 86KB LDS -> max 32 resident/XCD (1/CU).
// Each WG: g = physical XCC_ID, slot = atomicAdd(cnt[g]); slot>=32 -> exit (overlaunch spares
// guarantee every XCD accumulates exactly 32 stayers -> complete groups, no flag aliasing).
// Wave w4 computes gate w4 for 8 batches x 16 units; h ring + flags live in the XCD's L2.
__global__ __launch_bounds__(256, 1) void k_lstm(const float* __restrict__ whh,
                                                 const unsigned short* __restrict__ gates,
                                                 unsigned short* __restrict__ ring,
                                                 float* __restrict__ pooled,
                                                 int* __restrict__ flags,
                                                 int* __restrict__ cnt){
  __shared__ unsigned short Wl[64][512];   // 64KB: rows = gate*16+unit
  __shared__ f32x4 Dg[4*2*16];             // 2KB:  [gate][lc][unit]
  __shared__ float padlds[5120];           // 20KB pad -> 86KB total -> 1 WG/CU
  __shared__ int s_hdr[2];
  const int t = threadIdx.x, w4 = t >> 6, l = t & 63, lr = l & 15, lc = l >> 4;
  if ((int)blockIdx.x == -1) ((volatile float*)padlds)[0] = 1.f;  // keep padlds
  if (t == 0){
    unsigned xcc;
    asm volatile("s_getreg_b32 %0, hwreg(HW_REG_XCC_ID)" : "=s"(xcc));
    int g = (int)(xcc & 7);
    s_hdr[0] = g;
    s_hdr[1] = atomicAdd(&cnt[g], 1);      // device-scope claim
  }
  __syncthreads();
  const int g = s_hdr[0], slot = s_hdr[1];
  if (slot >= 32) return;                  // spare WG: free the CU immediately
  const int j0 = slot * 16;
  { // stage w_hh slice fp32->bf16, chunk swizzle phys = logical ^ (row&7)
    const int row = t >> 2;
    const int gate = row >> 4, u = row & 15;
    const float* src = whh + (size_t)(gate*512 + j0 + u) * 512;
    const int cbase = (t & 3) * 16;
    #pragma unroll
    for (int i = 0; i < 16; ++i){
      const int lch = cbase + i;
      float4 f0 = *(const float4*)(src + lch*8);
      float4 f1 = *(const float4*)(src + lch*8 + 4);
      const int pch = lch ^ (row & 7);
      *(ushort4*)&Wl[row][pch*8]     = f4tobf(f0);
      *(ushort4*)&Wl[row][pch*8 + 4] = f4tobf(f1);
    }
  }
  const int eb = t >> 4, eu = t & 15;      // elementwise ownership, t<128: (batch, unit)
  float cst = 0.f, pool = 0.f;
  unsigned long long gx = 0, nx = 0;
  if (t < 128)
    gx = *(const unsigned long long*)(gates + (size_t)(g*8 + eb)*2048 + (j0 + eu)*4);
  int* const myflag = &flags[(g*32 + slot)*16];
  int* const fpoll  = &flags[(g*32 + (t & 31))*16];
  __syncthreads();
  for (int st = 0; st < 512; ++st){
    if (st < 511 && t < 128)
      nx = *(const unsigned long long*)(gates + ((size_t)(st+1)*64 + g*8 + eb)*2048 + (j0 + eu)*4);
    if (st > 0){
      if (t < 32){
        int v, tries = 0;
        do {  // sc0 load: bypass L1, read the shared XCD L2 (group == XCD by construction)
          asm volatile("global_load_dword %0, %1, off sc0\n\ts_waitcnt vmcnt(0)"
                       : "=v"(v) : "v"(fpoll) : "memory");
        } while (v < st && ++tries < 20000);  // bounded: fail fast, never hang
      }
      __syncthreads();
    }
    // h(st) @ Wl^T : A rows = 8 batches (lr&7, duplicated), wave w4 = gate w4
    const unsigned short* ha = ring + (((size_t)st*8 + g) << 12) + (lr & 7)*512 + lc*8;
    f32x4 acc = (f32x4){0.f,0.f,0.f,0.f};
    #pragma unroll
    for (int kt = 0; kt < 16; ++kt){
      bf16x8 a = *(const bf16x8*)(ha + kt*32);                 // plain cached (write-once addr)
      bf16x8 b = *(const bf16x8*)&Wl[w4*16 + lr][(((kt*4) + lc) ^ (lr & 7)) * 8];
      acc = __builtin_amdgcn_mfma_f32_16x16x32_bf16(a, b, acc, 0, 0, 0);
    }
    if (lc < 2) Dg[(w4*2 + lc)*16 + lr] = acc;   // D: col=unit(lane&15), row=batch(lc*4+reg)
    __syncthreads();
    if (t < 128){
      union { unsigned long long q; unsigned short u[4]; } ga; ga.q = gx;
      const int dq = (eb >> 2)*16 + eu, dr = eb & 3;
      float gi = Dg[0*32 + dq][dr] + b2f(ga.u[0]);
      float gf = Dg[1*32 + dq][dr] + b2f(ga.u[1]);
      float gc = Dg[2*32 + dq][dr] + b2f(ga.u[2]);
      float go = Dg[3*32 + dq][dr] + b2f(ga.u[3]);
      float i_ = 1.f / (1.f + __expf(-gi));
      float f_ = 1.f / (1.f + __expf(-gf));
      float cg = fminf(fmaxf(gc, -20.f), 20.f);
      float e2 = __expf(2.f * cg);
      float g_ = (e2 - 1.f) / (e2 + 1.f);
      float o_ = 1.f / (1.f + __expf(-go));
      float cn = f_ * cst + i_ * g_;
      cst = cn;
      float ct = fminf(fmaxf(cn, -20.f), 20.f);
      float e2c = __expf(2.f * ct);
      float th = (e2c - 1.f) / (e2c + 1.f);
      float hh = o_ * th;
      pool += hh;
      if (st < 511)  // plain write-through store -> lands in this XCD's L2
        ring[(((size_t)(st+1)*8 + g) << 12) + eb*512 + j0 + eu] = f2bf(hh);
      gx = nx;
    }
    __syncthreads();   // pre-barrier vmcnt(0) drains h stores to L2 [m97-measured semantics]
    if (st < 511 && t == 0){
      int v = st + 1;
      asm volatile("global_store_dword %0, %1, off sc0"
                   :: "v"(myflag), "v"(v) : "memory");
    }
  }
  if (t < 128)
    pooled[(size_t)(g*8 + eb)*512 + j0 + eu] = pool * (1.f / 512.f);
}

// K6: out = log_sigmoid(pooled @ proj_w.T + proj_b)
__global__ __launch_bounds__(256) void k_final(const float* __restrict__ pooled,
                                               const float* __restrict__ w,
                                               const float* __restrict__ bias,
                                               float* __restrict__ out){
  const int n = blockIdx.x;
  __shared__ float pr[512];
  const int t = threadIdx.x;
  pr[t]       = pooled[(size_t)n*512 + t];
  pr[t + 256] = pooled[(size_t)n*512 + t + 256];
  __syncthreads();
  const float* wr = w + (size_t)t * 512;
  float s = bias[t];
  for (int i = 0; i < 512; i += 4){
    float4 f = *(const float4*)(wr + i);
    s += f.x*pr[i] + f.y*pr[i+1] + f.z*pr[i+2] + f.w*pr[i+3];
  }
  float rres = fminf(s, 0.f) - log1pf(__expf(-fabsf(s)));
  out[(size_t)n*256 + t] = rres;
}

extern "C" void kernel_launch(void* const* d_in, const int* in_sizes, int n_in,
                              void* d_out, int out_size, void* d_ws, size_t ws_size,
                              hipStream_t stream){
  const float* x      = (const float*)d_in[0];
  const float* in_w   = (const float*)d_in[1];
  const float* in_b   = (const float*)d_in[2];
  const float* mo_w   = (const float*)d_in[3];
  const float* mo_b   = (const float*)d_in[4];
  const float* w_ih   = (const float*)d_in[5];
  const float* w_hh   = (const float*)d_in[6];
  const float* b_ih   = (const float*)d_in[7];
  const float* b_hh   = (const float*)d_in[8];
  const float* proj_w = (const float*)d_in[9];
  const float* proj_b = (const float*)d_in[10];
  uint8_t* ws = (uint8_t*)d_ws;
  int*            flags  = (int*)(ws + 0x0);
  int*            cnt    = (int*)(ws + 0x4000);
  float*          pooled = (float*)(ws + 0x30000);
  unsigned short* wihbf  = (unsigned short*)(ws + 0x50000);
  unsigned short* comb   = (unsigned short*)(ws + 0x800000);  // doubles as h-ring in k_lstm
  unsigned short* gates  = (unsigned short*)(ws + 0x3000000);
  unsigned short* qbuf   = (unsigned short*)(ws + 0x3000000); // aliases gates (dead before k_gates)
  unsigned short* kbuf   = (unsigned short*)(ws + 0x4000000);
  unsigned short* vbuf   = (unsigned short*)(ws + 0x5000000);
  unsigned short* ctx    = (unsigned short*)(ws + 0x6000000);

  hipMemsetAsync(ws, 0, 0x4020, stream);  // flags + cnt
  hipLaunchKernelGGL(k_convert, dim3(9216),    dim3(256), 0, stream, w_ih, x, wihbf, comb);
  hipLaunchKernelGGL(k_qkv,     dim3(12, 512), dim3(256), 0, stream, comb, in_w, in_b, qbuf, kbuf, vbuf);
  hipLaunchKernelGGL(k_attn,    dim3(512),     dim3(256), 0, stream, qbuf, kbuf, vbuf, ctx);
  hipLaunchKernelGGL(k_outproj, dim3(4, 512),  dim3(256), 0, stream, ctx, mo_w, mo_b, comb);
  hipLaunchKernelGGL(k_gates,   dim3(16, 256), dim3(256), 0, stream, comb, wihbf, b_ih, b_hh, gates);
  hipMemsetAsync(comb, 0, 0x10000, stream);  // h-ring slot 0 = h(-1) = zeros (comb dead now)
  hipLaunchKernelGGL(k_lstm,    dim3(512),     dim3(256), 0, stream, w_hh, gates, comb, pooled, flags, cnt);
  hipLaunchKernelGGL(k_final,   dim3(64),      dim3(256), 0, stream, pooled, proj_w, proj_b, (float*)d_out);
}

// Round 6
// 1897.068 us; speedup vs baseline: 498.8947x; 498.8947x over previous
//
#include <hip/hip_runtime.h>
#include <hip/hip_bf16.h>
#include <stdint.h>

// Problem: S=512, N=64, E=256, NH=8, HD=32, LH=512.
// Pipeline: convert -> qkv -> attn -> outproj -> gates GEMM -> persistent LSTM -> final proj.
// R6 = R5 (XCD-local LSTM, overlaunch+claim, bounded poll) with flags reverted to the
// PROVEN R2/R3 primitive: __hip_atomic_store/load RELAXED+AGENT (coherence point).
// R5's sc0 asm store/load pair never became mutually visible -> every step ran to the
// 20k-try poll timeout (~1.9ms/step = 968ms). h data path (plain stores -> XCD L2,
// plain loads from peer CUs in same XCD) is kept: it was proven correct in R5.
// Ordering: h stores drain to L2 at the pre-barrier vmcnt(0); flag store (IC, slower
// path) issued after => flag visible implies h visible in reader's local L2.

typedef __attribute__((ext_vector_type(8))) short bf16x8;
typedef __attribute__((ext_vector_type(4))) float f32x4;

__device__ __forceinline__ unsigned short f2bf(float f){
  unsigned u = __float_as_uint(f);
  u += 0x7FFFu + ((u >> 16) & 1u);          // RNE
  return (unsigned short)(u >> 16);
}
__device__ __forceinline__ float b2f(unsigned short h){
  return __uint_as_float(((unsigned)h) << 16);
}
__device__ __forceinline__ ushort4 f4tobf(float4 f){
  ushort4 o; o.x=f2bf(f.x); o.y=f2bf(f.y); o.z=f2bf(f.z); o.w=f2bf(f.w); return o;
}

// ---------------- workspace layout (bytes) ----------------
// flags:    [0x0,      0x4000)   8 groups x 32 slots, 64B stride
// cnt:      [0x4000,   0x4020)   8 ints, per-XCD slot claim
// pooled:   [0x30000,  0x50000)  64x512 f32
// w_ih bf16:[0x50000,  0x250000)
// combined: [0x800000, 0x2800000) 32768x512 bf16; REUSED by k_lstm as h-ring:
//           ring[st][g] = 8KB (8 batches x 512 units bf16), 64KB/step, 32MB total
// gates:    [0x3000000,0xB000000) layout [m][u][gate] = m*2048 + u*4 + gate (aliases q/k/v/ctx)
// q:0x3000000 k:0x4000000 v:0x5000000 ctx:0x6000000 (each 16MB bf16)
// total required ws: 0xB000000 = 184,549,376 B

// K0: w_ih fp32->bf16, and x fp32 -> combined[:, 0:256] bf16
__global__ __launch_bounds__(256) void k_convert(const float* __restrict__ wih,
                                                 const float* __restrict__ x,
                                                 unsigned short* __restrict__ wih_bf,
                                                 unsigned short* __restrict__ comb){
  size_t i = ((size_t)blockIdx.x * 256 + threadIdx.x) * 4;
  if (i < 1048576){
    float4 f = *(const float4*)(wih + i);
    *(ushort4*)(wih_bf + i) = f4tobf(f);
  } else {
    size_t j = i - 1048576;
    if (j < 8388608){
      float4 f = *(const float4*)(x + j);
      size_t m = j >> 8, c = j & 255;
      *(ushort4*)(comb + m*512 + c) = f4tobf(f);
    }
  }
}

// K1: qkv = x @ in_proj_w.T + b ; scale folded into q; writes q/k [n][h][s][d], v transposed [n][h][d][s]
__global__ __launch_bounds__(256) void k_qkv(const unsigned short* __restrict__ xb,
                                             const float* __restrict__ w,
                                             const float* __restrict__ bias,
                                             unsigned short* __restrict__ q,
                                             unsigned short* __restrict__ kk,
                                             unsigned short* __restrict__ v){
  const int nt = blockIdx.x;    // 0..11
  const int mt = blockIdx.y;    // 0..511  (= s, since M-row = s*64+n)
  __shared__ unsigned short Bs[64][264];
  const int t = threadIdx.x;
  { // stage+convert B tile (in_proj_w rows nt*64..+64, k 0..256)
    int row = t >> 2, c0 = (t & 3) * 64;
    const float* src = w + (size_t)(nt*64 + row)*256 + c0;
    #pragma unroll
    for (int i = 0; i < 64; i += 4){
      float4 f = *(const float4*)(src + i);
      *(ushort4*)&Bs[row][c0 + i] = f4tobf(f);
    }
  }
  __syncthreads();
  const int w4 = t >> 6, l = t & 63, lr = l & 15, lc = l >> 4;
  f32x4 acc[4];
  #pragma unroll
  for (int i = 0; i < 4; ++i) acc[i] = (f32x4){0.f,0.f,0.f,0.f};
  const size_t arow = (size_t)(mt*64 + w4*16 + lr) * 512;  // A from combined (bf16 x)
  #pragma unroll
  for (int kt = 0; kt < 8; ++kt){
    bf16x8 a = *(const bf16x8*)(xb + arow + kt*32 + lc*8);
    #pragma unroll
    for (int n4 = 0; n4 < 4; ++n4){
      bf16x8 b = *(const bf16x8*)&Bs[n4*16 + lr][kt*32 + lc*8];
      acc[n4] = __builtin_amdgcn_mfma_f32_16x16x32_bf16(a, b, acc[n4], 0, 0, 0);
    }
  }
  const int s = mt;
  #pragma unroll
  for (int n4 = 0; n4 < 4; ++n4){
    int ncol = nt*64 + n4*16 + lr;
    float bv = bias[ncol];
    int which = ncol >> 8, rem = ncol & 255, hh = rem >> 5, d = rem & 31;
    #pragma unroll
    for (int reg = 0; reg < 4; ++reg){
      int nb = w4*16 + lc*4 + reg;   // batch
      float val = acc[n4][reg] + bv;
      if (which == 0){
        val *= 0.17677669529663687f;  // 1/sqrt(32)
        q[((size_t)(nb*8 + hh)*512 + s)*32 + d] = f2bf(val);
      } else if (which == 1){
        kk[((size_t)(nb*8 + hh)*512 + s)*32 + d] = f2bf(val);
      } else {
        v[((size_t)(nb*8 + hh)*32 + d)*512 + s] = f2bf(val);
      }
    }
  }
}

// K2: attention for one (n,h); Q-tile=32, full-S bf16 score strip in LDS, exp recomputed into PV A-frags
__global__ __launch_bounds__(256) void k_attn(const unsigned short* __restrict__ q,
                                              const unsigned short* __restrict__ k,
                                              const unsigned short* __restrict__ v,
                                              unsigned short* __restrict__ ctx){
  const int nh = blockIdx.x;
  const int n = nh >> 3, h = nh & 7;
  __shared__ unsigned short sc[32][520];
  __shared__ float red[32][8];
  __shared__ float rowmax[32], rowinv[32];
  const unsigned short* qb = q + (size_t)nh * 512 * 32;
  const unsigned short* kb = k + (size_t)nh * 512 * 32;
  const unsigned short* vb = v + (size_t)nh * 32 * 512;
  const int t = threadIdx.x, w4 = t >> 6, l = t & 63, lr = l & 15, lc = l >> 4;
  const int r = t >> 3, cc = t & 7;
  for (int qt = 0; qt < 16; ++qt){
    const int s0 = qt * 32;
    bf16x8 aq0 = *(const bf16x8*)(qb + (size_t)(s0 + lr)*32 + lc*8);
    bf16x8 aq1 = *(const bf16x8*)(qb + (size_t)(s0 + 16 + lr)*32 + lc*8);
    #pragma unroll
    for (int j = 0; j < 8; ++j){
      int ntl = w4*8 + j;
      bf16x8 bk = *(const bf16x8*)(kb + (size_t)(ntl*16 + lr)*32 + lc*8);
      f32x4 d0 = (f32x4){0.f,0.f,0.f,0.f}, d1 = (f32x4){0.f,0.f,0.f,0.f};
      d0 = __builtin_amdgcn_mfma_f32_16x16x32_bf16(aq0, bk, d0, 0, 0, 0);
      d1 = __builtin_amdgcn_mfma_f32_16x16x32_bf16(aq1, bk, d1, 0, 0, 0);
      #pragma unroll
      for (int reg = 0; reg < 4; ++reg){
        sc[lc*4 + reg][ntl*16 + lr]      = f2bf(d0[reg]);
        sc[16 + lc*4 + reg][ntl*16 + lr] = f2bf(d1[reg]);
      }
    }
    __syncthreads();
    float pm = -1e30f;
    for (int i = 0; i < 64; ++i) pm = fmaxf(pm, b2f(sc[r][cc + 8*i]));
    red[r][cc] = pm;
    __syncthreads();
    float mfull = red[r][0];
    #pragma unroll
    for (int i = 1; i < 8; ++i) mfull = fmaxf(mfull, red[r][i]);
    rowmax[r] = mfull;   // benign same-value race across the 8 threads of a row
    __syncthreads();
    float sum = 0.f;
    for (int i = 0; i < 64; ++i) sum += __expf(b2f(sc[r][cc + 8*i]) - mfull);
    red[r][cc] = sum;
    __syncthreads();
    float ss = 0.f;
    #pragma unroll
    for (int i = 0; i < 8; ++i) ss += red[r][i];
    rowinv[r] = 1.f / ss;
    __syncthreads();
    // PV: each wave one 16x16 tile of the 32x32 O
    const int mt = w4 >> 1, ntd = w4 & 1;
    const int arow = mt*16 + lr;
    const float mrow = rowmax[arow];
    f32x4 o = (f32x4){0.f,0.f,0.f,0.f};
    for (int kt = 0; kt < 16; ++kt){
      bf16x8 sv = *(const bf16x8*)&sc[arow][kt*32 + lc*8];
      bf16x8 ap;
      #pragma unroll
      for (int e = 0; e < 8; ++e){
        float p = __expf(b2f((unsigned short)sv[e]) - mrow);
        ap[e] = (short)f2bf(p);
      }
      bf16x8 bv = *(const bf16x8*)(vb + (size_t)(ntd*16 + lr)*512 + kt*32 + lc*8);
      o = __builtin_amdgcn_mfma_f32_16x16x32_bf16(ap, bv, o, 0, 0, 0);
    }
    #pragma unroll
    for (int reg = 0; reg < 4; ++reg){
      int row = mt*16 + lc*4 + reg;
      int d = ntd*16 + lr;
      float val = o[reg] * rowinv[row];
      ctx[((size_t)(s0 + row)*64 + n)*256 + h*32 + d] = f2bf(val);
    }
    __syncthreads();
  }
}

// K3: attn_out = ctx @ mha_out_w.T + b -> combined[:, 256:512]
__global__ __launch_bounds__(256) void k_outproj(const unsigned short* __restrict__ ctx,
                                                 const float* __restrict__ w,
                                                 const float* __restrict__ bias,
                                                 unsigned short* __restrict__ comb){
  const int nt = blockIdx.x;   // 0..3
  const int mt = blockIdx.y;   // 0..511
  __shared__ unsigned short Bs[64][264];
  const int t = threadIdx.x;
  {
    int row = t >> 2, c0 = (t & 3) * 64;
    const float* src = w + (size_t)(nt*64 + row)*256 + c0;
    #pragma unroll
    for (int i = 0; i < 64; i += 4){
      float4 f = *(const float4*)(src + i);
      *(ushort4*)&Bs[row][c0 + i] = f4tobf(f);
    }
  }
  __syncthreads();
  const int w4 = t >> 6, l = t & 63, lr = l & 15, lc = l >> 4;
  f32x4 acc[4];
  #pragma unroll
  for (int i = 0; i < 4; ++i) acc[i] = (f32x4){0.f,0.f,0.f,0.f};
  const size_t arow = (size_t)(mt*64 + w4*16 + lr) * 256;
  #pragma unroll
  for (int kt = 0; kt < 8; ++kt){
    bf16x8 a = *(const bf16x8*)(ctx + arow + kt*32 + lc*8);
    #pragma unroll
    for (int n4 = 0; n4 < 4; ++n4){
      bf16x8 b = *(const bf16x8*)&Bs[n4*16 + lr][kt*32 + lc*8];
      acc[n4] = __builtin_amdgcn_mfma_f32_16x16x32_bf16(a, b, acc[n4], 0, 0, 0);
    }
  }
  #pragma unroll
  for (int n4 = 0; n4 < 4; ++n4){
    int ncol = nt*64 + n4*16 + lr;
    float bv = bias[ncol];
    #pragma unroll
    for (int reg = 0; reg < 4; ++reg){
      int m = mt*64 + w4*16 + lc*4 + reg;
      comb[(size_t)m*512 + 256 + ncol] = f2bf(acc[n4][reg] + bv);
    }
  }
}

// K4: gates_x = combined @ w_ih.T + (b_ih + b_hh), 128x128 tiles, BK=64.
// Output layout for k_lstm: gates[m][u][gate] = m*2048 + u*4 + gate  (m = st*64 + n).
__global__ __launch_bounds__(256) void k_gates(const unsigned short* __restrict__ A,
                                               const unsigned short* __restrict__ B,
                                               const float* __restrict__ bih,
                                               const float* __restrict__ bhh,
                                               unsigned short* __restrict__ gates){
  const int ntile = blockIdx.x;  // 0..15
  const int mtile = blockIdx.y;  // 0..255
  __shared__ unsigned short As[128][72], Bss[128][72];
  const int t = threadIdx.x, w4 = t >> 6, l = t & 63, lr = l & 15, lc = l >> 4;
  const int wm = w4 >> 1, wn = w4 & 1;
  f32x4 acc[4][4];
  #pragma unroll
  for (int i = 0; i < 4; ++i)
    #pragma unroll
    for (int j = 0; j < 4; ++j) acc[i][j] = (f32x4){0.f,0.f,0.f,0.f};
  const int srow = t >> 1, half = t & 1;
  const unsigned short* sa = A + (size_t)(mtile*128 + srow)*512 + half*32;
  const unsigned short* sb = B + (size_t)(ntile*128 + srow)*512 + half*32;
  for (int kkk = 0; kkk < 8; ++kkk){
    #pragma unroll
    for (int i = 0; i < 4; ++i){
      *(uint4*)&As [srow][half*32 + i*8] = *(const uint4*)(sa + kkk*64 + i*8);
      *(uint4*)&Bss[srow][half*32 + i*8] = *(const uint4*)(sb + kkk*64 + i*8);
    }
    __syncthreads();
    #pragma unroll
    for (int kt = 0; kt < 2; ++kt){
      bf16x8 af[4], bfr[4];
      #pragma unroll
      for (int i = 0; i < 4; ++i) af[i]  = *(const bf16x8*)&As [wm*64 + i*16 + lr][kt*32 + lc*8];
      #pragma unroll
      for (int i = 0; i < 4; ++i) bfr[i] = *(const bf16x8*)&Bss[wn*64 + i*16 + lr][kt*32 + lc*8];
      #pragma unroll
      for (int i = 0; i < 4; ++i)
        #pragma unroll
        for (int j = 0; j < 4; ++j)
          acc[i][j] = __builtin_amdgcn_mfma_f32_16x16x32_bf16(af[i], bfr[j], acc[i][j], 0, 0, 0);
    }
    __syncthreads();
  }
  #pragma unroll
  for (int i = 0; i < 4; ++i){
    #pragma unroll
    for (int j = 0; j < 4; ++j){
      int ncol = ntile*128 + wn*64 + j*16 + lr;
      int gate = ncol >> 9, u = ncol & 511;
      float bsum = bih[ncol] + bhh[ncol];
      #pragma unroll
      for (int reg = 0; reg < 4; ++reg){
        int m = mtile*128 + wm*64 + i*16 + lc*4 + reg;
        gates[(size_t)m*2048 + u*4 + gate] = f2bf(acc[i][j][reg] + bsum);
      }
    }
  }
}

// K5: persistent LSTM, XCD-local. Launch 512 WGs; 86KB LDS -> max 32 resident/XCD (1/CU).
// Each WG: g = physical XCC_ID, slot = atomicAdd(cnt[g]); slot>=32 -> exit (overlaunch spares
// guarantee every XCD accumulates exactly 32 stayers -> complete groups, no flag aliasing).
// h ring: plain stores (write-through -> local L2), plain loads by same-XCD peers (R5-proven).
// Flags: __hip_atomic AGENT scope (R2/R3-proven visible); flag-visible => h in local L2.
__global__ __launch_bounds__(256, 1) void k_lstm(const float* __restrict__ whh,
                                                 const unsigned short* __restrict__ gates,
                                                 unsigned short* __restrict__ ring,
                                                 float* __restrict__ pooled,
                                                 int* __restrict__ flags,
                                                 int* __restrict__ cnt){
  __shared__ unsigned short Wl[64][512];   // 64KB: rows = gate*16+unit
  __shared__ f32x4 Dg[4*2*16];             // 2KB:  [gate][lc][unit]
  __shared__ float padlds[5120];           // 20KB pad -> 86KB total -> 1 WG/CU
  __shared__ int s_hdr[2];
  const int t = threadIdx.x, w4 = t >> 6, l = t & 63, lr = l & 15, lc = l >> 4;
  if ((int)blockIdx.x == -1) ((volatile float*)padlds)[0] = 1.f;  // keep padlds
  if (t == 0){
    unsigned xcc;
    asm volatile("s_getreg_b32 %0, hwreg(HW_REG_XCC_ID)" : "=s"(xcc));
    int g = (int)(xcc & 7);
    s_hdr[0] = g;
    s_hdr[1] = atomicAdd(&cnt[g], 1);      // device-scope claim
  }
  __syncthreads();
  const int g = s_hdr[0], slot = s_hdr[1];
  if (slot >= 32) return;                  // spare WG: free the CU immediately
  const int j0 = slot * 16;
  { // stage w_hh slice fp32->bf16, chunk swizzle phys = logical ^ (row&7)
    const int row = t >> 2;
    const int gate = row >> 4, u = row & 15;
    const float* src = whh + (size_t)(gate*512 + j0 + u) * 512;
    const int cbase = (t & 3) * 16;
    #pragma unroll
    for (int i = 0; i < 16; ++i){
      const int lch = cbase + i;
      float4 f0 = *(const float4*)(src + lch*8);
      float4 f1 = *(const float4*)(src + lch*8 + 4);
      const int pch = lch ^ (row & 7);
      *(ushort4*)&Wl[row][pch*8]     = f4tobf(f0);
      *(ushort4*)&Wl[row][pch*8 + 4] = f4tobf(f1);
    }
  }
  const int eb = t >> 4, eu = t & 15;      // elementwise ownership, t<128: (batch, unit)
  float cst = 0.f, pool = 0.f;
  unsigned long long gx = 0, nx = 0;
  if (t < 128)
    gx = *(const unsigned long long*)(gates + (size_t)(g*8 + eb)*2048 + (j0 + eu)*4);
  int* const myflag = &flags[(g*32 + slot)*16];
  int* const fpoll  = &flags[(g*32 + (t & 31))*16];
  __syncthreads();
  for (int st = 0; st < 512; ++st){
    if (st < 511 && t < 128)
      nx = *(const unsigned long long*)(gates + ((size_t)(st+1)*64 + g*8 + eb)*2048 + (j0 + eu)*4);
    if (st > 0){
      if (t < 32){
        int tries = 0;   // bounded: fail fast (correct-by-delay), never hang
        while (__hip_atomic_load(fpoll, __ATOMIC_RELAXED, __HIP_MEMORY_SCOPE_AGENT) < st
               && ++tries < 5000) { }
      }
      __syncthreads();
    }
    // h(st) @ Wl^T : A rows = 8 batches (lr&7, duplicated), wave w4 = gate w4
    const unsigned short* ha = ring + (((size_t)st*8 + g) << 12) + (lr & 7)*512 + lc*8;
    f32x4 acc = (f32x4){0.f,0.f,0.f,0.f};
    #pragma unroll
    for (int kt = 0; kt < 16; ++kt){
      bf16x8 a = *(const bf16x8*)(ha + kt*32);                 // plain cached (write-once addr)
      bf16x8 b = *(const bf16x8*)&Wl[w4*16 + lr][(((kt*4) + lc) ^ (lr & 7)) * 8];
      acc = __builtin_amdgcn_mfma_f32_16x16x32_bf16(a, b, acc, 0, 0, 0);
    }
    if (lc < 2) Dg[(w4*2 + lc)*16 + lr] = acc;   // D: col=unit(lane&15), row=batch(lc*4+reg)
    __syncthreads();
    if (t < 128){
      union { unsigned long long q; unsigned short u[4]; } ga; ga.q = gx;
      const int dq = (eb >> 2)*16 + eu, dr = eb & 3;
      float gi = Dg[0*32 + dq][dr] + b2f(ga.u[0]);
      float gf = Dg[1*32 + dq][dr] + b2f(ga.u[1]);
      float gc = Dg[2*32 + dq][dr] + b2f(ga.u[2]);
      float go = Dg[3*32 + dq][dr] + b2f(ga.u[3]);
      float i_ = 1.f / (1.f + __expf(-gi));
      float f_ = 1.f / (1.f + __expf(-gf));
      float cg = fminf(fmaxf(gc, -20.f), 20.f);
      float e2 = __expf(2.f * cg);
      float g_ = (e2 - 1.f) / (e2 + 1.f);
      float o_ = 1.f / (1.f + __expf(-go));
      float cn = f_ * cst + i_ * g_;
      cst = cn;
      float ct = fminf(fmaxf(cn, -20.f), 20.f);
      float e2c = __expf(2.f * ct);
      float th = (e2c - 1.f) / (e2c + 1.f);
      float hh = o_ * th;
      pool += hh;
      if (st < 511)  // plain write-through store -> lands in this XCD's L2
        ring[(((size_t)(st+1)*8 + g) << 12) + eb*512 + j0 + eu] = f2bf(hh);
      gx = nx;
    }
    __syncthreads();   // pre-barrier vmcnt(0) drains h stores to L2 [m97-measured semantics]
    if (st < 511 && t == 0){
      __hip_atomic_store(myflag, st + 1, __ATOMIC_RELAXED, __HIP_MEMORY_SCOPE_AGENT);
    }
  }
  if (t < 128)
    pooled[(size_t)(g*8 + eb)*512 + j0 + eu] = pool * (1.f / 512.f);
}

// K6: out = log_sigmoid(pooled @ proj_w.T + proj_b)
__global__ __launch_bounds__(256) void k_final(const float* __restrict__ pooled,
                                               const float* __restrict__ w,
                                               const float* __restrict__ bias,
                                               float* __restrict__ out){
  const int n = blockIdx.x;
  __shared__ float pr[512];
  const int t = threadIdx.x;
  pr[t]       = pooled[(size_t)n*512 + t];
  pr[t + 256] = pooled[(size_t)n*512 + t + 256];
  __syncthreads();
  const float* wr = w + (size_t)t * 512;
  float s = bias[t];
  for (int i = 0; i < 512; i += 4){
    float4 f = *(const float4*)(wr + i);
    s += f.x*pr[i] + f.y*pr[i+1] + f.z*pr[i+2] + f.w*pr[i+3];
  }
  float rres = fminf(s, 0.f) - log1pf(__expf(-fabsf(s)));
  out[(size_t)n*256 + t] = rres;
}

extern "C" void kernel_launch(void* const* d_in, const int* in_sizes, int n_in,
                              void* d_out, int out_size, void* d_ws, size_t ws_size,
                              hipStream_t stream){
  const float* x      = (const float*)d_in[0];
  const float* in_w   = (const float*)d_in[1];
  const float* in_b   = (const float*)d_in[2];
  const float* mo_w   = (const float*)d_in[3];
  const float* mo_b   = (const float*)d_in[4];
  const float* w_ih   = (const float*)d_in[5];
  const float* w_hh   = (const float*)d_in[6];
  const float* b_ih   = (const float*)d_in[7];
  const float* b_hh   = (const float*)d_in[8];
  const float* proj_w = (const float*)d_in[9];
  const float* proj_b = (const float*)d_in[10];
  uint8_t* ws = (uint8_t*)d_ws;
  int*            flags  = (int*)(ws + 0x0);
  int*            cnt    = (int*)(ws + 0x4000);
  float*          pooled = (float*)(ws + 0x30000);
  unsigned short* wihbf  = (unsigned short*)(ws + 0x50000);
  unsigned short* comb   = (unsigned short*)(ws + 0x800000);  // doubles as h-ring in k_lstm
  unsigned short* gates  = (unsigned short*)(ws + 0x3000000);
  unsigned short* qbuf   = (unsigned short*)(ws + 0x3000000); // aliases gates (dead before k_gates)
  unsigned short* kbuf   = (unsigned short*)(ws + 0x4000000);
  unsigned short* vbuf   = (unsigned short*)(ws + 0x5000000);
  unsigned short* ctx    = (unsigned short*)(ws + 0x6000000);

  hipMemsetAsync(ws, 0, 0x4020, stream);  // flags + cnt
  hipLaunchKernelGGL(k_convert, dim3(9216),    dim3(256), 0, stream, w_ih, x, wihbf, comb);
  hipLaunchKernelGGL(k_qkv,     dim3(12, 512), dim3(256), 0, stream, comb, in_w, in_b, qbuf, kbuf, vbuf);
  hipLaunchKernelGGL(k_attn,    dim3(512),     dim3(256), 0, stream, qbuf, kbuf, vbuf, ctx);
  hipLaunchKernelGGL(k_outproj, dim3(4, 512),  dim3(256), 0, stream, ctx, mo_w, mo_b, comb);
  hipLaunchKernelGGL(k_gates,   dim3(16, 256), dim3(256), 0, stream, comb, wihbf, b_ih, b_hh, gates);
  hipMemsetAsync(comb, 0, 0x10000, stream);  // h-ring slot 0 = h(-1) = zeros (comb dead now)
  hipLaunchKernelGGL(k_lstm,    dim3(512),     dim3(256), 0, stream, w_hh, gates, comb, pooled, flags, cnt);
  hipLaunchKernelGGL(k_final,   dim3(64),      dim3(256), 0, stream, pooled, proj_w, proj_b, (float*)d_out);
}